// Round 7
// baseline (94.383 us; speedup 1.0000x reference)
//
#include <hip/hip_runtime.h>
#include <hip/hip_bf16.h>

// out = exp(Q K^T) V, unnormalized. B=4, S=4096, D=64, fp32 in/out.
// Round 7: barrier-free register streaming. Rounds 3-6 (LDS-staged, 1-3
// barriers/iter) all pinned at ~3000 cyc/CU/tile -> the staging discipline
// (DMA -> vmcnt(0) -> s_barrier, all waves coupled) is the plateau, per the
// m97 lesson. prep stores K fp16 / V bf16 in EXACT 32x32x16 fragment order,
// so waves load fragments straight into VGPRs from L2 (1MB/batch working
// set, L2-resident; ~32KB/tile/CU after L1 absorbs in-block 2x redundancy).
// 256 blocks x 8 waves, register double-buffered tile prefetch, NO in-loop
// barriers, LDS only for the one-time epilogue cross-kkq reduce.
// No kk-split -> reduce kernel deleted. __expf (not prescale+exp2) to
// restore the 4.4x absmax margin (round 6's prescale cut it to 1.47x).

typedef short    s16x4 __attribute__((ext_vector_type(4)));
typedef short    s16x8 __attribute__((ext_vector_type(8)));
typedef _Float16 h16x8 __attribute__((ext_vector_type(8)));
typedef float    fx4   __attribute__((ext_vector_type(4)));
typedef float    fx16  __attribute__((ext_vector_type(16)));

constexpr int S = 4096, D = 64, BN = 128;
constexpr int TILES = S / BN;                       // 32
constexpr int TILE_SHORTS  = 16 * 512;              // 16KB (8192 shorts)/array/tile
constexpr int BATCH_SHORTS = TILES * TILE_SHORTS;   // 262144

__device__ __forceinline__ unsigned short f2bf(float x) {
    unsigned u = __float_as_uint(x);
    u = (u + 0x7FFFu + ((u >> 16) & 1u)) >> 16;   // RNE
    return (unsigned short)u;
}
__device__ __forceinline__ float bf2f(unsigned short h) {
    return __uint_as_float(((unsigned)h) << 16);
}
__device__ __forceinline__ unsigned short f2h(float x) {
    union { _Float16 h; unsigned short s; } u;
    u.h = (_Float16)x;
    return u.s;
}
__device__ __forceinline__ unsigned pack_bf16(float lo, float hi) {
    __hip_bfloat162 r = __float22bfloat162_rn(make_float2(lo, hi));
    union { __hip_bfloat162 b; unsigned u; } c;
    c.b = r;
    return c.u;
}
__device__ __forceinline__ h16x8 as_h16(s16x8 x) {
    union { s16x8 s; h16x8 h; } u;
    u.s = x;
    return u.h;
}

// -------- prep: K -> fp16 A-frag order, V -> bf16 B-frag order (32x32x16) ---
// K chunk c = kkq*4+ks : [lane][j] = K[t*128 + kkq*32 + (lane&31)][ks*16 + (lane>>5)*8 + j]
// V chunk c = ss*2+dt  : [lane][j] = V[t*128 + ss*16 + (lane>>5)*8 + j][dt*32 + (lane&31)]
__global__ __launch_bounds__(256) void prep2(
    const float* __restrict__ k, const float* __restrict__ v,
    unsigned short* __restrict__ kf, unsigned short* __restrict__ vf)
{
    __shared__ unsigned short tile[128 * 72];   // row stride 72 halves (pad)
    const int tid   = threadIdx.x;
    const int which = blockIdx.x & 1;           // 0 = K, 1 = V
    const int t     = (blockIdx.x >> 1) & 31;
    const int b     = blockIdx.x >> 6;
    const float* src = (which ? v : k) + ((size_t)b * S + t * BN) * D;

    #pragma unroll
    for (int i = 0; i < 8; ++i) {               // coalesced: 2048 float4s/block
        int f   = i * 256 + tid;
        int row = f >> 4;
        int c4  = (f & 15) << 2;
        float4 x = *(const float4*)(src + row * D + c4);
        s16x4 o;
        if (which) o = (s16x4){(short)f2bf(x.x), (short)f2bf(x.y),
                               (short)f2bf(x.z), (short)f2bf(x.w)};
        else       o = (s16x4){(short)f2h(x.x), (short)f2h(x.y),
                               (short)f2h(x.z), (short)f2h(x.w)};
        *(s16x4*)&tile[row * 72 + c4] = o;
    }
    __syncthreads();

    const int lane = tid & 63;
    unsigned short* dst = (which ? vf : kf) + (size_t)b * BATCH_SHORTS + t * TILE_SHORTS;
    #pragma unroll
    for (int i = 0; i < 4; ++i) {
        int c = (tid >> 6) * 4 + i;             // chunk 0..15
        s16x8 o;
        if (which == 0) {
            int row = (c >> 2) * 32 + (lane & 31);
            int dc  = (c & 3) * 16 + (lane >> 5) * 8;
            o = *(const s16x8*)&tile[row * 72 + dc];     // b128, aligned
        } else {
            int r0 = (c >> 1) * 16 + (lane >> 5) * 8;
            int dc = (c & 1) * 32 + (lane & 31);
            #pragma unroll
            for (int j = 0; j < 8; ++j) o[j] = (short)tile[(r0 + j) * 72 + dc];
        }
        *(s16x8*)(dst + c * 512 + lane * 8) = o;         // coalesced b128
    }
}

// ---------------- main: barrier-free register streaming ----------------
__global__ __launch_bounds__(512, 2) void attn_stream(
    const float* __restrict__ q, const unsigned short* __restrict__ kf,
    const unsigned short* __restrict__ vf, float* __restrict__ out)
{
    __shared__ float scratch[6 * 2048];   // 48KB, epilogue reduce only

    const int tid = threadIdx.x, lane = tid & 63, w = tid >> 6;
    const int h = lane >> 5, m5 = lane & 31;
    const int mt = w & 1, kkq = w >> 1;         // m-tile (32 rows), kk-quarter
    const int b = blockIdx.y, q0 = blockIdx.x * 64;

    // Wave's fragment streams: K chunks kkq*4+i and V chunks kkq*4+i
    // (i = u*2+dt for V: exactly the 4 chunks this wave's GEMM2 needs).
    const unsigned short* kq = kf + (size_t)b * BATCH_SHORTS + (kkq * 4) * 512 + lane * 8;
    const unsigned short* vq = vf + (size_t)b * BATCH_SHORTS + (kkq * 4) * 512 + lane * 8;

    // Q B-frags fp16 (no prescale): B[k=h*8+j][n=m5] = Q[q0+mt*32+m5][ks*16+h*8+j]
    h16x8 qf[4];
    {
        const float* qrow = q + ((size_t)b * S + q0 + mt * 32 + m5) * D + h * 8;
        #pragma unroll
        for (int ks = 0; ks < 4; ++ks) {
            float4 a = *(const float4*)(qrow + ks * 16);
            float4 c = *(const float4*)(qrow + ks * 16 + 4);
            qf[ks] = (h16x8){(_Float16)a.x, (_Float16)a.y, (_Float16)a.z, (_Float16)a.w,
                             (_Float16)c.x, (_Float16)c.y, (_Float16)c.z, (_Float16)c.w};
        }
    }

    fx16 oacc[2] = {};   // [dt] O[mt*32.., dt*32..], partial over kkq

    s16x8 ka[4], va[4], kb[4], vb[4];   // double-buffered fragment registers

    auto ldfrag = [&](int t, s16x8* kd, s16x8* vd) {
        const size_t off = (size_t)t * TILE_SHORTS;
        #pragma unroll
        for (int i = 0; i < 4; ++i) {
            kd[i] = *(const s16x8*)(kq + off + i * 512);
            vd[i] = *(const s16x8*)(vq + off + i * 512);
        }
    };

    auto compute = [&](const s16x8* kc, const s16x8* vc) {
        // ---- GEMM1 (fp16 32x32x16): Sc^T[kk 32][m 32], contraction d=64 ----
        fx16 sa = {};
        #pragma unroll
        for (int ks = 0; ks < 4; ++ks)
            sa = __builtin_amdgcn_mfma_f32_32x32x16_f16(as_h16(kc[ks]), qf[ks], sa, 0, 0, 0);

        // ---- P = exp(Sc^T), bf16-pair packed. C-layout: kk=(r&3)+8*(r>>2)+4h, m=m5 ----
        unsigned p01[8];
        #pragma unroll
        for (int rp = 0; rp < 8; ++rp)
            p01[rp] = pack_bf16(__expf(sa[2 * rp]), __expf(sa[2 * rp + 1]));

        // ---- C-layout -> GEMM2 A-layout: cross-half (lane^32) exchange ----
        union frag { unsigned u[4]; s16x8 v; };
        frag A[2];
#if __has_builtin(__builtin_amdgcn_permlane32_swap)
        typedef unsigned uix2 __attribute__((ext_vector_type(2)));
        uix2 r0 = __builtin_amdgcn_permlane32_swap(p01[0], p01[2], false, false);
        uix2 r1 = __builtin_amdgcn_permlane32_swap(p01[1], p01[3], false, false);
        A[0].u[0] = r0.x; A[0].u[1] = r1.x; A[0].u[2] = r0.y; A[0].u[3] = r1.y;
        uix2 r2 = __builtin_amdgcn_permlane32_swap(p01[4], p01[6], false, false);
        uix2 r3 = __builtin_amdgcn_permlane32_swap(p01[5], p01[7], false, false);
        A[1].u[0] = r2.x; A[1].u[1] = r3.x; A[1].u[2] = r2.y; A[1].u[3] = r3.y;
#else
        unsigned sw[8];
        #pragma unroll
        for (int rp = 0; rp < 8; ++rp)
            sw[rp] = (unsigned)__shfl_xor((int)p01[rp], 32, 64);
        A[0].u[0] = h ? sw[2]   : p01[0];
        A[0].u[1] = h ? sw[3]   : p01[1];
        A[0].u[2] = h ? p01[2]  : sw[0];
        A[0].u[3] = h ? p01[3]  : sw[1];
        A[1].u[0] = h ? sw[6]   : p01[4];
        A[1].u[1] = h ? sw[7]   : p01[5];
        A[1].u[2] = h ? p01[6]  : sw[4];
        A[1].u[3] = h ? p01[7]  : sw[5];
#endif

        // ---- GEMM2 (bf16 32x32x16): O += P*V over this wave's 32 kk ----
        #pragma unroll
        for (int u = 0; u < 2; ++u)
            #pragma unroll
            for (int dt = 0; dt < 2; ++dt)
                oacc[dt] = __builtin_amdgcn_mfma_f32_32x32x16_bf16(
                    A[u].v, vc[u * 2 + dt], oacc[dt], 0, 0, 0);
    };

    ldfrag(0, ka, va);
    #pragma unroll 1
    for (int t = 0; t < TILES; t += 2) {
        ldfrag(t + 1, kb, vb);              // in flight across compute(ka)
        compute(ka, va);
        ldfrag((t + 2) & (TILES - 1), ka, va);   // in flight across compute(kb)
        compute(kb, vb);
    }

    // ---- epilogue: reduce 4 kkq partials per m-tile through LDS, store ----
    if (kkq > 0) {
        float* dst = scratch + (size_t)(mt * 3 + (kkq - 1)) * 2048;
        #pragma unroll
        for (int dt = 0; dt < 2; ++dt)
            #pragma unroll
            for (int r = 0; r < 16; ++r)
                dst[(dt * 16 + r) * 64 + lane] = oacc[dt][r];
    }
    __syncthreads();
    if (kkq == 0) {
        float* ob = out + (size_t)b * S * D;
        #pragma unroll
        for (int dt = 0; dt < 2; ++dt)
            #pragma unroll
            for (int r = 0; r < 16; ++r) {
                float val = oacc[dt][r];
                #pragma unroll
                for (int p = 0; p < 3; ++p)
                    val += scratch[(size_t)(mt * 3 + p) * 2048 + (dt * 16 + r) * 64 + lane];
                int row = q0 + mt * 32 + (r & 3) + 8 * (r >> 2) + 4 * h;
                ob[(size_t)row * D + dt * 32 + m5] = val;
            }
    }
}

// ---------------- fallback (known-good round-2 kernel) ----------------
__global__ __launch_bounds__(1024) void attn_fallback(
    const float* __restrict__ q, const float* __restrict__ k,
    const float* __restrict__ v, float* __restrict__ out)
{
    __shared__ unsigned short Kh[64][72];
    __shared__ unsigned short Kl[64][72];
    __shared__ unsigned short Vt[64][68];
    __shared__ unsigned short Pf[64][72];

    const int tid = threadIdx.x, lane = tid & 63, wave = tid >> 6;
    const int quad = lane >> 4, tq = lane & 15;
    const int kkb = wave & 3, mba = wave >> 2;
    const int b = blockIdx.y, q0 = blockIdx.x * 64;
    const float* qb = q + (size_t)b * S * D;
    const float* kb = k + (size_t)b * S * D;
    const float* vb = v + (size_t)b * S * D;
    float* ob = out + (size_t)b * S * D;

    s16x8 qh[2], ql[2];
    {
        const float* qrow = qb + (size_t)(q0 + mba * 16 + tq) * D;
        #pragma unroll
        for (int ks = 0; ks < 2; ++ks) {
            const float* src = qrow + ks * 32 + quad * 8;
            float4 f0 = *(const float4*)src;
            float4 f1 = *(const float4*)(src + 4);
            float f[8] = {f0.x, f0.y, f0.z, f0.w, f1.x, f1.y, f1.z, f1.w};
            #pragma unroll
            for (int j = 0; j < 8; ++j) {
                unsigned short hh = f2bf(f[j]);
                qh[ks][j] = (short)hh;
                ql[ks][j] = (short)f2bf(f[j] - bf2f(hh));
            }
        }
    }
    fx4 oacc = {0.f, 0.f, 0.f, 0.f};
    const int krow = tid >> 4, kc4 = (tid & 15) << 2;
    const int vd = tid & 63, vk = (tid >> 6) << 2;

    for (int t = 0; t < S / 64; ++t) {
        __syncthreads();
        const float* kt = kb + (size_t)(t * 64 + krow) * D;
        const float* vt = vb + (size_t)(t * 64 + vk) * D;
        {
            float4 kv = *(const float4*)(kt + kc4);
            unsigned short h0 = f2bf(kv.x), h1 = f2bf(kv.y), h2 = f2bf(kv.z), h3 = f2bf(kv.w);
            s16x4 a = {(short)h0, (short)h1, (short)h2, (short)h3};
            s16x4 l4 = {(short)f2bf(kv.x - bf2f(h0)), (short)f2bf(kv.y - bf2f(h1)),
                        (short)f2bf(kv.z - bf2f(h2)), (short)f2bf(kv.w - bf2f(h3))};
            *(s16x4*)&Kh[krow][kc4] = a;
            *(s16x4*)&Kl[krow][kc4] = l4;
            const float* vs = vt + vd;
            s16x4 vv = {(short)f2bf(vs[0]), (short)f2bf(vs[D]),
                        (short)f2bf(vs[2 * D]), (short)f2bf(vs[3 * D])};
            *(s16x4*)&Vt[vd][vk] = vv;
        }
        __syncthreads();
        fx4 sacc = {0.f, 0.f, 0.f, 0.f};
        #pragma unroll
        for (int ks = 0; ks < 2; ++ks) {
            s16x8 kah = *(const s16x8*)&Kh[kkb * 16 + tq][ks * 32 + quad * 8];
            s16x8 kal = *(const s16x8*)&Kl[kkb * 16 + tq][ks * 32 + quad * 8];
            sacc = __builtin_amdgcn_mfma_f32_16x16x32_bf16(kah, qh[ks], sacc, 0, 0, 0);
            sacc = __builtin_amdgcn_mfma_f32_16x16x32_bf16(kah, ql[ks], sacc, 0, 0, 0);
            sacc = __builtin_amdgcn_mfma_f32_16x16x32_bf16(kal, qh[ks], sacc, 0, 0, 0);
        }
        s16x4 pp = {(short)f2bf(__expf(sacc[0])), (short)f2bf(__expf(sacc[1])),
                    (short)f2bf(__expf(sacc[2])), (short)f2bf(__expf(sacc[3]))};
        *(s16x4*)&Pf[mba * 16 + tq][kkb * 16 + (quad << 2)] = pp;
        __syncthreads();
        #pragma unroll
        for (int ks = 0; ks < 2; ++ks) {
            s16x8 pa = *(const s16x8*)&Pf[mba * 16 + tq][ks * 32 + quad * 8];
            const unsigned short* vr = &Vt[kkb * 16 + tq][ks * 32 + quad * 8];
            s16x4 va = *(const s16x4*)vr;
            s16x4 vb2 = *(const s16x4*)(vr + 4);
            s16x8 vfull = __builtin_shufflevector(va, vb2, 0, 1, 2, 3, 4, 5, 6, 7);
            oacc = __builtin_amdgcn_mfma_f32_16x16x32_bf16(pa, vfull, oacc, 0, 0, 0);
        }
    }
    #pragma unroll
    for (int r = 0; r < 4; ++r)
        ob[(size_t)(q0 + mba * 16 + quad * 4 + r) * D + kkb * 16 + tq] = oacc[r];
}

extern "C" void kernel_launch(void* const* d_in, const int* in_sizes, int n_in,
                              void* d_out, int out_size, void* d_ws, size_t ws_size,
                              hipStream_t stream) {
    const float* q = (const float*)d_in[0];
    const float* k = (const float*)d_in[1];
    const float* v = (const float*)d_in[2];
    float* out = (float*)d_out;
    const int nbatch = in_sizes[0] / (S * D);   // 4
    const size_t elems = (size_t)nbatch * S * D;

    // ws: kf (fp16, 2MB) | vf (bf16, 2MB)
    const size_t need = elems * 2 * 2;
    if (nbatch == 4 && ws_size >= need && d_ws != nullptr) {
        unsigned short* kf = (unsigned short*)d_ws;
        unsigned short* vf = kf + elems;

        prep2<<<nbatch * TILES * 2, 256, 0, stream>>>(k, v, kf, vf);
        dim3 grid(S / 64, nbatch);
        attn_stream<<<grid, 512, 0, stream>>>(q, kf, vf, out);
    } else {
        dim3 grid(S / 64, nbatch);
        attn_fallback<<<grid, 1024, 0, stream>>>(q, k, v, out);
    }
}